// Round 16
// baseline (155.644 us; speedup 1.0000x reference)
//
#include <hip/hip_runtime.h>
#include <cstdint>

#define HW_ 4096

typedef __attribute__((ext_vector_type(8))) short bf16x8;
typedef __attribute__((ext_vector_type(4))) short bf16x4;
typedef __attribute__((ext_vector_type(4))) float f32x4;

static __device__ __forceinline__ unsigned short f2bf(float f) {
  unsigned u = __builtin_bit_cast(unsigned, f);
  u += 0x7FFF + ((u >> 16) & 1);
  return (unsigned short)(u >> 16);
}
static __device__ __forceinline__ float bf2f(unsigned short u) {
  return __builtin_bit_cast(float, (unsigned)u << 16);
}
static __device__ __forceinline__ float ldf(const float* p) { return *p; }
static __device__ __forceinline__ float ldf(const unsigned short* p) { return bf2f(*p); }

static __device__ __forceinline__ void gl_lds16(const unsigned short* g,
                                                unsigned short* s) {
  __builtin_amdgcn_global_load_lds(
      (const __attribute__((address_space(1))) unsigned int*)g,
      (__attribute__((address_space(3))) unsigned int*)s, 16, 0, 0);
}

// ---------- fused depthwise 3x3 (pad1) + bf16 + transpose -> XT[b][p][c] ----------
// DO_PREP z==8 slice: wbuf rows = [q 0..255 | k perm (h*32+d) | v perm | out_pw],
// plus bias_pre.  (R11-identical)
template <typename T, int DO_PREP>
__global__ __launch_bounds__(256) void dwconv_t_kernel(
    const T* __restrict__ x, const float* __restrict__ w9,
    unsigned short* __restrict__ xT,
    const float* __restrict__ pw1, const float* __restrict__ pw2,
    unsigned short* __restrict__ wb, const float* __restrict__ btab,
    const int* __restrict__ relidx, float* __restrict__ bias_pre) {
  if (DO_PREP && blockIdx.z == 8) {
    int idx0 = (blockIdx.y * 64 + blockIdx.x) * 256 + threadIdx.x;  // 0..65535
#pragma unroll
    for (int k = 0; k < 12; ++k) {
      int idx = idx0 + k * 65536;                 // 786432 items total
      if (idx < 65536) {
        wb[idx] = f2bf(pw1[idx]);                 // q rows 0..255 (unpermuted)
      } else if (idx < 131072) {                  // k rows, permuted to h*32+d
        int t = idx - 65536;
        int row = t >> 8, col = t & 255;
        int h = row >> 5, d = row & 31;
        wb[idx] = f2bf(pw1[(256 + d * 8 + h) * 256 + col]);
      } else if (idx < 196608) {                  // v rows, permuted to h*32+d
        int t = idx - 131072;
        int row = t >> 8, col = t & 255;
        int h = row >> 5, d = row & 31;
        wb[idx] = f2bf(pw1[(512 + d * 8 + h) * 256 + col]);
      } else if (idx < 262144) {
        wb[idx] = f2bf(pw2[idx - 196608]);        // out_pw rows 768..1023
      } else {
        int t = idx - 262144;                     // h*65536 + g*256 + j
        int j = t & 255, g = (t >> 8) & 255, h = t >> 16;
        bias_pre[t] = btab[relidx[g * 256 + j] * 8 + h] * 0.03125f;
      }
    }
    return;
  }
  __shared__ unsigned short lds_t[64][66];
  int iy = blockIdx.x;
  int cg = blockIdx.y;
  int b  = blockIdx.z;
  int tid = threadIdx.x;
  int px  = tid & 63;
  int cl0 = (tid >> 6) * 16;
  const T* xrow = x + (size_t)b * 256 * HW_ + iy * 64 + px;
#pragma unroll 4
  for (int e = 0; e < 16; ++e) {
    int c = cg * 64 + cl0 + e;
    const T* xp = xrow + (size_t)c * HW_;
    const float* wp = w9 + c * 9;
    float v0 = (iy > 0)  ? ldf(xp - 64) : 0.f;
    float v1 = ldf(xp);
    float v2 = (iy < 63) ? ldf(xp + 64) : 0.f;
    float l0 = __shfl(v0, px - 1, 64), r0 = __shfl(v0, px + 1, 64);
    float l1 = __shfl(v1, px - 1, 64), r1 = __shfl(v1, px + 1, 64);
    float l2 = __shfl(v2, px - 1, 64), r2 = __shfl(v2, px + 1, 64);
    if (px == 0)  { l0 = 0.f; l1 = 0.f; l2 = 0.f; }
    if (px == 63) { r0 = 0.f; r1 = 0.f; r2 = 0.f; }
    float acc = l0 * wp[0] + v0 * wp[1] + r0 * wp[2]
              + l1 * wp[3] + v1 * wp[4] + r1 * wp[5]
              + l2 * wp[6] + v2 * wp[7] + r2 * wp[8];
    lds_t[cl0 + e][px] = f2bf(acc);
  }
  __syncthreads();
#pragma unroll
  for (int j = 0; j < 2; ++j) {
    int flat = tid + j * 256;
    int rpx = flat >> 3, cseg = flat & 7;
    unsigned v0 = (unsigned)lds_t[cseg*8+0][rpx] | ((unsigned)lds_t[cseg*8+1][rpx] << 16);
    unsigned v1 = (unsigned)lds_t[cseg*8+2][rpx] | ((unsigned)lds_t[cseg*8+3][rpx] << 16);
    unsigned v2 = (unsigned)lds_t[cseg*8+4][rpx] | ((unsigned)lds_t[cseg*8+5][rpx] << 16);
    unsigned v3 = (unsigned)lds_t[cseg*8+6][rpx] | ((unsigned)lds_t[cseg*8+7][rpx] << 16);
    uint4 pk = {v0, v1, v2, v3};
    *(uint4*)(xT + ((size_t)b * 4096 + iy * 64 + rpx) * 256 + cg * 64 + cseg * 8) = pk;
  }
}

// ---------- pointwise conv as bf16 MFMA GEMM (LDS unioned, 36 KB) ----------
// OUT_BF16=1: bf16 store via Cs staging (q path). OUT_BF16=0: fp32 out via
// LDS-staged f32x4 nontemporal stores (2 halves). KV=1: y==2 produces XDS.
template <int OUT_BF16, int KV>
__global__ __launch_bounds__(256) void pwconv_mfma_kernel(
    const unsigned short* __restrict__ XT, const unsigned short* __restrict__ W,
    void* __restrict__ Yv, int OC, unsigned short* __restrict__ xds) {
  __shared__ unsigned short smem[18432];   // 36 KB union
  unsigned short* As = smem;               // 128x64
  unsigned short* Bs = smem + 8192;        // 128x64
  int tid = threadIdx.x;
  int b = blockIdx.z;
  if (KV && blockIdx.y == 2) {
    if (blockIdx.x >= 8) return;
    int j0 = blockIdx.x * 32;
    int jloc = tid >> 3, icg = tid & 7;
    int j = j0 + jloc;
    int oy = j >> 4, ox = j & 15;
    const float s = 63.0f / 15.0f;
    float ys = oy * s, xf = ox * s;
    int y0 = (int)ys, x0 = (int)xf;
    int y1 = min(y0 + 1, 63), x1 = min(x0 + 1, 63);
    float wy = ys - (float)y0, wx = xf - (float)x0;
    float w00 = (1.f - wy) * (1.f - wx), w01 = (1.f - wy) * wx;
    float w10 = wy * (1.f - wx), w11 = wy * wx;
    const unsigned short* base = XT + (size_t)b * 4096 * 256 + icg * 32;
    const bf16x8* p00 = (const bf16x8*)(base + (size_t)(y0 * 64 + x0) * 256);
    const bf16x8* p01 = (const bf16x8*)(base + (size_t)(y0 * 64 + x1) * 256);
    const bf16x8* p10 = (const bf16x8*)(base + (size_t)(y1 * 64 + x0) * 256);
    const bf16x8* p11 = (const bf16x8*)(base + (size_t)(y1 * 64 + x1) * 256);
    unsigned short* xo = xds + ((size_t)(b * 256 + j)) * 256 + icg * 32;
#pragma unroll
    for (int q = 0; q < 4; ++q) {
      bf16x8 a00 = p00[q], a01 = p01[q], a10 = p10[q], a11 = p11[q];
      unsigned rp[4];
#pragma unroll
      for (int e2 = 0; e2 < 4; ++e2) {
        float f0 = w00 * bf2f((unsigned short)a00[2*e2])   + w01 * bf2f((unsigned short)a01[2*e2])
                 + w10 * bf2f((unsigned short)a10[2*e2])   + w11 * bf2f((unsigned short)a11[2*e2]);
        float f1 = w00 * bf2f((unsigned short)a00[2*e2+1]) + w01 * bf2f((unsigned short)a01[2*e2+1])
                 + w10 * bf2f((unsigned short)a10[2*e2+1]) + w11 * bf2f((unsigned short)a11[2*e2+1]);
        rp[e2] = (unsigned)f2bf(f0) | ((unsigned)f2bf(f1) << 16);
      }
      uint4 pk = {rp[0], rp[1], rp[2], rp[3]};
      *(uint4*)(xo + q * 8) = pk;
    }
    return;
  }
  int oc0 = blockIdx.y * 128, p0 = blockIdx.x * 128;
  int w = tid >> 6, l = tid & 63;
  int wm = w >> 1, wn = w & 1;
  int lr = l & 15, lg = l >> 4;
  const unsigned short* Wp = W + (size_t)oc0 * 256;
  const unsigned short* Xp = XT + ((size_t)b * 4096 + p0) * 256;
  f32x4 acc[4][4] = {};
  for (int kt = 0; kt < 4; ++kt) {
    int k0 = kt * 64;
#pragma unroll
    for (int j = 0; j < 4; ++j) {
      int chunk = w * 4 + j;            // wave-uniform
      int row = chunk * 8 + (l >> 3);
      int lcu = (l & 7) ^ (row & 7);    // inverse-swizzled source column
      gl_lds16(Wp + (size_t)row * 256 + k0 + lcu * 8, &As[chunk * 512]);
      gl_lds16(Xp + (size_t)row * 256 + k0 + lcu * 8, &Bs[chunk * 512]);
    }
    __syncthreads();
#pragma unroll
    for (int ks = 0; ks < 2; ++ks) {
      bf16x8 af[4], bfr[4];
      int ku = ks * 4 + lg;
#pragma unroll
      for (int mi = 0; mi < 4; ++mi) {
        int row = wm * 64 + mi * 16 + lr;
        af[mi] = *(const bf16x8*)&As[row * 64 + (ku ^ (row & 7)) * 8];
      }
#pragma unroll
      for (int ni = 0; ni < 4; ++ni) {
        int row = wn * 64 + ni * 16 + lr;
        bfr[ni] = *(const bf16x8*)&Bs[row * 64 + (ku ^ (row & 7)) * 8];
      }
#pragma unroll
      for (int mi = 0; mi < 4; ++mi)
#pragma unroll
        for (int ni = 0; ni < 4; ++ni)
          acc[mi][ni] = __builtin_amdgcn_mfma_f32_16x16x32_bf16(
              af[mi], bfr[ni], acc[mi][ni], 0, 0, 0);
    }
    __syncthreads();
  }
  // D: col(l&15) = p-local, row((l>>4)*4+reg) = oc-local
  if constexpr (OUT_BF16) {
    unsigned short (*Cs)[136] = (unsigned short(*)[136])smem;  // union, post-sync
#pragma unroll
    for (int mi = 0; mi < 4; ++mi)
#pragma unroll
      for (int ni = 0; ni < 4; ++ni)
#pragma unroll
        for (int r = 0; r < 4; ++r)
          Cs[wm * 64 + mi * 16 + lg * 4 + r][wn * 64 + ni * 16 + lr] =
              f2bf(acc[mi][ni][r]);
    __syncthreads();
    unsigned short* Yb = (unsigned short*)Yv + (size_t)b * OC * HW_;
    int pc = tid & 15, ocr = tid >> 4;
#pragma unroll
    for (int it = 0; it < 8; ++it) {
      int oc = it * 16 + ocr;
      uint4 pk = *(const uint4*)&Cs[oc][pc * 8];
      *(uint4*)(Yb + (size_t)(oc0 + oc) * HW_ + p0 + pc * 8) = pk;
    }
  } else {
    // fp32 out: LDS-stage 64-row halves -> f32x4 nontemporal stores
    float (*Cf)[132] = (float(*)[132])smem;   // 64 x 132 f32 = 33792 B (<=36864)
    float* Yb = (float*)Yv + (size_t)b * OC * HW_;
#pragma unroll
    for (int hh = 0; hh < 2; ++hh) {
      if (wm == hh) {
#pragma unroll
        for (int mi = 0; mi < 4; ++mi)
#pragma unroll
          for (int ni = 0; ni < 4; ++ni)
#pragma unroll
            for (int r = 0; r < 4; ++r)
              Cf[mi * 16 + lg * 4 + r][wn * 64 + ni * 16 + lr] = acc[mi][ni][r];
      }
      __syncthreads();
#pragma unroll
      for (int it = 0; it < 8; ++it) {
        int flat = tid + it * 256;          // 2048 f32x4 units
        int row = flat >> 5, seg = flat & 31;
        f32x4 pk = *(const f32x4*)&Cf[row][seg * 4];
        __builtin_nontemporal_store(
            pk, (f32x4*)(Yb + (size_t)(oc0 + hh * 64 + row) * HW_ + p0 + seg * 4));
      }
      __syncthreads();
    }
  }
}

// ---------- kv GEMM on XDS: 128x128x256 MFMA + LN/vfrag epilogue (R11-identical) ----
__global__ __launch_bounds__(256) void kv_gemm_kernel(
    const unsigned short* __restrict__ XDS, const unsigned short* __restrict__ W,
    const float* __restrict__ gk, const float* __restrict__ bk,
    unsigned short* __restrict__ kln, unsigned short* __restrict__ vfrag) {
  __shared__ unsigned short smem[18432];
  unsigned short* As = smem;
  unsigned short* Bs = smem + 8192;
  int tid = threadIdx.x;
  int b = blockIdx.z, yv = blockIdx.y;
  int oc0 = yv * 128, p0 = blockIdx.x * 128;
  int w = tid >> 6, l = tid & 63;
  int wm = w >> 1, wn = w & 1;
  int lr = l & 15, lg = l >> 4;
  const unsigned short* Wp = W + (size_t)oc0 * 256;
  const unsigned short* Xp = XDS + ((size_t)b * 256 + p0) * 256;
  f32x4 acc[4][4] = {};
  for (int kt = 0; kt < 4; ++kt) {
    int k0 = kt * 64;
#pragma unroll
    for (int j = 0; j < 4; ++j) {
      int chunk = w * 4 + j;
      int row = chunk * 8 + (l >> 3);
      int lcu = (l & 7) ^ (row & 7);
      gl_lds16(Wp + (size_t)row * 256 + k0 + lcu * 8, &As[chunk * 512]);
      gl_lds16(Xp + (size_t)row * 256 + k0 + lcu * 8, &Bs[chunk * 512]);
    }
    __syncthreads();
#pragma unroll
    for (int ks = 0; ks < 2; ++ks) {
      bf16x8 af[4], bfr[4];
      int ku = ks * 4 + lg;
#pragma unroll
      for (int mi = 0; mi < 4; ++mi) {
        int row = wm * 64 + mi * 16 + lr;
        af[mi] = *(const bf16x8*)&As[row * 64 + (ku ^ (row & 7)) * 8];
      }
#pragma unroll
      for (int ni = 0; ni < 4; ++ni) {
        int row = wn * 64 + ni * 16 + lr;
        bfr[ni] = *(const bf16x8*)&Bs[row * 64 + (ku ^ (row & 7)) * 8];
      }
#pragma unroll
      for (int mi = 0; mi < 4; ++mi)
#pragma unroll
        for (int ni = 0; ni < 4; ++ni)
          acc[mi][ni] = __builtin_amdgcn_mfma_f32_16x16x32_bf16(
              af[mi], bfr[ni], acc[mi][ni], 0, 0, 0);
    }
    __syncthreads();
  }
  unsigned short (*Cs)[136] = (unsigned short(*)[136])smem;
#pragma unroll
  for (int mi = 0; mi < 4; ++mi)
#pragma unroll
    for (int ni = 0; ni < 4; ++ni)
#pragma unroll
      for (int r = 0; r < 4; ++r)
        Cs[wm * 64 + mi * 16 + lg * 4 + r][wn * 64 + ni * 16 + lr] =
            f2bf(acc[mi][ni][r]);
  __syncthreads();
  int hl = tid >> 6;          // wave id = h-local
  int jl = tid & 63;
  if (yv < 2) {
    int h = yv * 4 + hl;
    int bh = b * 8 + h;
#pragma unroll
    for (int jj = 0; jj < 2; ++jj) {
      int jc = jl * 2 + jj;
      int j = p0 + jc;
      float v[32];
      float s1 = 0.f, s2 = 0.f;
#pragma unroll
      for (int d = 0; d < 32; ++d) {
        v[d] = bf2f(Cs[hl * 32 + d][jc]);
        s1 += v[d]; s2 += v[d] * v[d];
      }
      float mu = s1 * (1.f / 32.f);
      float var = s2 * (1.f / 32.f) - mu * mu;
      float inv = 1.0f / sqrtf(var + 1e-6f);
      unsigned rp[16];
#pragma unroll
      for (int t = 0; t < 16; ++t) {
        float y0f = (v[2*t]   - mu) * inv * gk[h*32 + 2*t]   + bk[h*32 + 2*t];
        float y1f = (v[2*t+1] - mu) * inv * gk[h*32 + 2*t+1] + bk[h*32 + 2*t+1];
        rp[t] = (unsigned)f2bf(y0f) | ((unsigned)f2bf(y1f) << 16);
      }
      uint4* ko = (uint4*)(kln + ((size_t)bh * 256 + j) * 32);
#pragma unroll
      for (int t4 = 0; t4 < 4; ++t4) {
        uint4 pk = {rp[t4*4], rp[t4*4+1], rp[t4*4+2], rp[t4*4+3]};
        ko[t4] = pk;
      }
    }
  } else {
    int h = (yv - 2) * 4 + hl;
    int bh = b * 8 + h;
#pragma unroll
    for (int jj = 0; jj < 2; ++jj) {
      int jc = jl * 2 + jj;
      int j = p0 + jc;
      int c = j >> 4, gq2 = (j >> 2) & 3, ii = j & 3;
      unsigned short* vo = vfrag + (size_t)bh * 8192;
#pragma unroll
      for (int d = 0; d < 32; ++d) {
        int dt = d >> 4, dr = d & 15;
        vo[(c * 2 + dt) * 256 + (gq2 * 16 + dr) * 4 + ii] = Cs[hl * 32 + d][jc];
      }
    }
  }
}

// ---------------- MFMA attention: LDS-staged q tile + fused q-LayerNorm ----------
__global__ __launch_bounds__(256) void attn_mfma_kernel(
    const unsigned short* __restrict__ qb, const float* __restrict__ gq,
    const float* __restrict__ bq, const unsigned short* __restrict__ kln,
    const unsigned short* __restrict__ vfrag, const float* __restrict__ bias_pre,
    float* __restrict__ attn_out, unsigned short* __restrict__ out_nchw) {
  __shared__ unsigned short qs[32][66];   // q tile: row d, col q-local (padded)
  __shared__ unsigned short sT[32][72];   // out stage (16B-aligned rows)
  int tile = blockIdx.x, h = blockIdx.y, b = blockIdx.z;
  int bh = b * 8 + h;
  int tid = threadIdx.x;
  int w = tid >> 6, l = tid & 63;
  int lr = l & 15, lg = l >> 4;
  int qbase = tile * 64 + w * 16;
  int q = qbase + lr;
  int iy = q >> 6, ix = q & 63;
  int g = (iy >> 2) * 16 + (ix >> 2);

  // cooperative q tile load: 32 rows (d) x 64 q-pixels, each row 128 B contiguous
  {
    const unsigned short* qrow = qb + (size_t)b * 256 * HW_ + tile * 64;
#pragma unroll
    for (int it = 0; it < 4; ++it) {
      int flat = tid + it * 256;        // 0..1023
      int d = flat >> 5;                // 0..31
      int cp = flat & 31;               // col pair (2 ushorts)
      *(unsigned*)&qs[d][cp * 2] =
          *(const unsigned*)(qrow + (size_t)(d * 8 + h) * HW_ + cp * 2);
    }
  }
  __syncthreads();

  // fused q LayerNorm from LDS
  float qv[8];
  float sum = 0.f, sum2 = 0.f;
#pragma unroll
  for (int e = 0; e < 8; ++e) {
    qv[e] = bf2f(qs[lg * 8 + e][w * 16 + lr]);
    sum += qv[e]; sum2 += qv[e] * qv[e];
  }
  sum  += __shfl_xor(sum, 16, 64);  sum  += __shfl_xor(sum, 32, 64);
  sum2 += __shfl_xor(sum2, 16, 64); sum2 += __shfl_xor(sum2, 32, 64);
  float mu = sum * (1.f / 32.f);
  float var = sum2 * (1.f / 32.f) - mu * mu;
  float inv = 1.0f / sqrtf(var + 1e-6f);
  bf16x8 qf;
#pragma unroll
  for (int e = 0; e < 8; ++e) {
    int d = lg * 8 + e;
    float y = (qv[e] - mu) * inv * gq[h * 32 + d] + bq[h * 32 + d];
    qf[e] = (short)f2bf(y);
  }

  const unsigned short* kbase = kln + (size_t)bh * 256 * 32 + lr * 32 + lg * 8;
  const unsigned short* vbase = vfrag + (size_t)bh * 32 * 256 + l * 4;
  const float* bbase = bias_pre + ((size_t)h * 256 + g) * 256 + lg * 4;
  float* abase = attn_out + ((size_t)bh * 4096 + q) * 256 + lg * 4;

  f32x4 z = {0.f, 0.f, 0.f, 0.f};
  f32x4 oacc0 = z, oacc1 = z;
#pragma unroll
  for (int c = 0; c < 16; ++c) {
    bf16x8 kf = *(const bf16x8*)(kbase + c * 16 * 32);
    f32x4 bias = *(const f32x4*)(bbase + c * 16);
    bf16x4 va0 = *(const bf16x4*)(vbase + (c * 2 + 0) * 256);
    bf16x4 va1 = *(const bf16x4*)(vbase + (c * 2 + 1) * 256);
    __builtin_amdgcn_s_setprio(1);
    f32x4 s = __builtin_amdgcn_mfma_f32_16x16x32_bf16(kf, qf, z, 0, 0, 0);
    f32x4 t = s * 0.03125f + bias;
    bf16x4 pb;
    pb[0] = (short)f2bf(t.x);
    pb[1] = (short)f2bf(t.y);
    pb[2] = (short)f2bf(t.z);
    pb[3] = (short)f2bf(t.w);
    oacc0 = __builtin_amdgcn_mfma_f32_16x16x16bf16_1k(va0, pb, oacc0, 0, 0, 0);
    oacc1 = __builtin_amdgcn_mfma_f32_16x16x16bf16_1k(va1, pb, oacc1, 0, 0, 0);
    __builtin_amdgcn_s_setprio(0);
    __builtin_nontemporal_store(t, (f32x4*)(abase + c * 16));
  }
  // stage out tile [32 d][64 q] in LDS, then 128-B coalesced stores
  float ov[8] = {oacc0.x, oacc0.y, oacc0.z, oacc0.w,
                 oacc1.x, oacc1.y, oacc1.z, oacc1.w};
#pragma unroll
  for (int dt = 0; dt < 2; ++dt)
#pragma unroll
    for (int r = 0; r < 4; ++r)
      sT[dt * 16 + lg * 4 + r][w * 16 + lr] = f2bf(ov[dt * 4 + r]);
  __syncthreads();
  {
    int row = tid >> 3, seg = tid & 7;       // 32 d-rows x 8 segs x 16 B
    uint4 pk = *(const uint4*)&sT[row][seg * 8];
    int cc = row * 8 + h;
    *(uint4*)(out_nchw + ((size_t)b * 256 + cc) * HW_ + tile * 64 + seg * 8) = pk;
  }
}

extern "C" void kernel_launch(void* const* d_in, const int* in_sizes, int n_in,
                              void* d_out, int out_size, void* d_ws, size_t ws_size,
                              hipStream_t stream) {
  const float* x      = (const float*)d_in[0];
  const float* qkv_dw = (const float*)d_in[1];
  const float* qkv_pw = (const float*)d_in[2];
  const float* out_dw = (const float*)d_in[3];
  const float* out_pw = (const float*)d_in[4];
  const float* gq     = (const float*)d_in[5];
  const float* bq     = (const float*)d_in[6];
  const float* gk     = (const float*)d_in[7];
  const float* bk     = (const float*)d_in[8];
  const float* btab   = (const float*)d_in[9];
  const int*   relidx = (const int*)d_in[10];

  float* out  = (float*)d_out;            // 8,388,608 floats
  float* attn = out + 8388608;            // 67,108,864 floats (268 MB)

  unsigned short* us = (unsigned short*)d_ws;
  unsigned short* xT1    = us;                    // 16.8 MB
  unsigned short* xT2    = us + 8388608;          // 16.8 MB
  unsigned short* onchwb = us + 16777216;         // 16.8 MB
  unsigned short* kln    = us + 25165824;         // 1 MB
  unsigned short* vfrag  = us + 25690112;         // 1 MB
  unsigned short* wbuf   = us + 26214400;         // 0.5 MB
  float* bias_pre = (float*)(us + 26476544);      // 2 MB
  unsigned short* qb     = us + 27525120;         // 16.8 MB (q only)
  unsigned short* xds    = us + 35913728;         // 1 MB

  dwconv_t_kernel<float, 1><<<dim3(64, 4, 9), 256, 0, stream>>>(
      x, qkv_dw, xT1, qkv_pw, out_pw, wbuf, btab, relidx, bias_pre);
  pwconv_mfma_kernel<1, 1><<<dim3(32, 3, 8), 256, 0, stream>>>(
      xT1, wbuf, qb, 256, xds);
  kv_gemm_kernel<<<dim3(2, 4, 8), 256, 0, stream>>>(
      xds, wbuf + 65536, gk, bk, kln, vfrag);
  attn_mfma_kernel<<<dim3(64, 8, 8), 256, 0, stream>>>(qb, gq, bq, kln, vfrag,
                                                       bias_pre, attn, onchwb);
  dwconv_t_kernel<unsigned short, 0><<<dim3(64, 4, 8), 256, 0, stream>>>(
      onchwb, out_dw, xT2, nullptr, nullptr, nullptr, nullptr, nullptr, nullptr);
  pwconv_mfma_kernel<0, 0><<<dim3(32, 2, 8), 256, 0, stream>>>(
      xT2, wbuf + 196608, out, 256, nullptr);
}

// Round 17
// 148.681 us; speedup vs baseline: 1.0468x; 1.0468x over previous
//
#include <hip/hip_runtime.h>
#include <cstdint>

#define HW_ 4096

typedef __attribute__((ext_vector_type(8))) short bf16x8;
typedef __attribute__((ext_vector_type(4))) short bf16x4;
typedef __attribute__((ext_vector_type(4))) float f32x4;

static __device__ __forceinline__ unsigned short f2bf(float f) {
  unsigned u = __builtin_bit_cast(unsigned, f);
  u += 0x7FFF + ((u >> 16) & 1);
  return (unsigned short)(u >> 16);
}
static __device__ __forceinline__ float bf2f(unsigned short u) {
  return __builtin_bit_cast(float, (unsigned)u << 16);
}
static __device__ __forceinline__ float ldf(const float* p) { return *p; }
static __device__ __forceinline__ float ldf(const unsigned short* p) { return bf2f(*p); }

static __device__ __forceinline__ void gl_lds16(const unsigned short* g,
                                                unsigned short* s) {
  __builtin_amdgcn_global_load_lds(
      (const __attribute__((address_space(1))) unsigned int*)g,
      (__attribute__((address_space(3))) unsigned int*)s, 16, 0, 0);
}

// ---------- fused depthwise 3x3 (pad1) + bf16 + transpose -> XT[b][p][c] ----------
// DO_PREP z==8 slice: wbuf rows = [q 0..255 | k perm (h*32+d) | v perm | out_pw],
// plus bias_pre.
template <typename T, int DO_PREP>
__global__ __launch_bounds__(256) void dwconv_t_kernel(
    const T* __restrict__ x, const float* __restrict__ w9,
    unsigned short* __restrict__ xT,
    const float* __restrict__ pw1, const float* __restrict__ pw2,
    unsigned short* __restrict__ wb, const float* __restrict__ btab,
    const int* __restrict__ relidx, float* __restrict__ bias_pre) {
  if (DO_PREP && blockIdx.z == 8) {
    int idx0 = (blockIdx.y * 64 + blockIdx.x) * 256 + threadIdx.x;  // 0..65535
#pragma unroll
    for (int k = 0; k < 12; ++k) {
      int idx = idx0 + k * 65536;                 // 786432 items total
      if (idx < 65536) {
        wb[idx] = f2bf(pw1[idx]);                 // q rows 0..255 (unpermuted)
      } else if (idx < 131072) {                  // k rows, permuted to h*32+d
        int t = idx - 65536;
        int row = t >> 8, col = t & 255;
        int h = row >> 5, d = row & 31;
        wb[idx] = f2bf(pw1[(256 + d * 8 + h) * 256 + col]);
      } else if (idx < 196608) {                  // v rows, permuted to h*32+d
        int t = idx - 131072;
        int row = t >> 8, col = t & 255;
        int h = row >> 5, d = row & 31;
        wb[idx] = f2bf(pw1[(512 + d * 8 + h) * 256 + col]);
      } else if (idx < 262144) {
        wb[idx] = f2bf(pw2[idx - 196608]);        // out_pw rows 768..1023
      } else {
        int t = idx - 262144;                     // h*65536 + g*256 + j
        int j = t & 255, g = (t >> 8) & 255, h = t >> 16;
        bias_pre[t] = btab[relidx[g * 256 + j] * 8 + h] * 0.03125f;
      }
    }
    return;
  }
  __shared__ unsigned short lds_t[64][66];
  int iy = blockIdx.x;
  int cg = blockIdx.y;
  int b  = blockIdx.z;
  int tid = threadIdx.x;
  int px  = tid & 63;
  int cl0 = (tid >> 6) * 16;
  const T* xrow = x + (size_t)b * 256 * HW_ + iy * 64 + px;
#pragma unroll 4
  for (int e = 0; e < 16; ++e) {
    int c = cg * 64 + cl0 + e;
    const T* xp = xrow + (size_t)c * HW_;
    const float* wp = w9 + c * 9;
    float v0 = (iy > 0)  ? ldf(xp - 64) : 0.f;
    float v1 = ldf(xp);
    float v2 = (iy < 63) ? ldf(xp + 64) : 0.f;
    float l0 = __shfl(v0, px - 1, 64), r0 = __shfl(v0, px + 1, 64);
    float l1 = __shfl(v1, px - 1, 64), r1 = __shfl(v1, px + 1, 64);
    float l2 = __shfl(v2, px - 1, 64), r2 = __shfl(v2, px + 1, 64);
    if (px == 0)  { l0 = 0.f; l1 = 0.f; l2 = 0.f; }
    if (px == 63) { r0 = 0.f; r1 = 0.f; r2 = 0.f; }
    float acc = l0 * wp[0] + v0 * wp[1] + r0 * wp[2]
              + l1 * wp[3] + v1 * wp[4] + r1 * wp[5]
              + l2 * wp[6] + v2 * wp[7] + r2 * wp[8];
    lds_t[cl0 + e][px] = f2bf(acc);
  }
  __syncthreads();
#pragma unroll
  for (int j = 0; j < 2; ++j) {
    int flat = tid + j * 256;
    int rpx = flat >> 3, cseg = flat & 7;
    unsigned v0 = (unsigned)lds_t[cseg*8+0][rpx] | ((unsigned)lds_t[cseg*8+1][rpx] << 16);
    unsigned v1 = (unsigned)lds_t[cseg*8+2][rpx] | ((unsigned)lds_t[cseg*8+3][rpx] << 16);
    unsigned v2 = (unsigned)lds_t[cseg*8+4][rpx] | ((unsigned)lds_t[cseg*8+5][rpx] << 16);
    unsigned v3 = (unsigned)lds_t[cseg*8+6][rpx] | ((unsigned)lds_t[cseg*8+7][rpx] << 16);
    uint4 pk = {v0, v1, v2, v3};
    *(uint4*)(xT + ((size_t)b * 4096 + iy * 64 + rpx) * 256 + cg * 64 + cseg * 8) = pk;
  }
}

// ---------- pointwise conv as bf16 MFMA GEMM (LDS unioned, 36 KB) ----------
// OUT_BF16: bf16 store via Cs staging. KV=1: blockIdx.y==2 produces XDS.
template <int OUT_BF16, int KV>
__global__ __launch_bounds__(256) void pwconv_mfma_kernel(
    const unsigned short* __restrict__ XT, const unsigned short* __restrict__ W,
    void* __restrict__ Yv, int OC, unsigned short* __restrict__ xds) {
  __shared__ unsigned short smem[18432];   // 36 KB union
  unsigned short* As = smem;               // 128x64
  unsigned short* Bs = smem + 8192;        // 128x64
  int tid = threadIdx.x;
  int b = blockIdx.z;
  if (KV && blockIdx.y == 2) {
    if (blockIdx.x >= 8) return;
    int j0 = blockIdx.x * 32;
    int jloc = tid >> 3, icg = tid & 7;
    int j = j0 + jloc;
    int oy = j >> 4, ox = j & 15;
    const float s = 63.0f / 15.0f;
    float ys = oy * s, xf = ox * s;
    int y0 = (int)ys, x0 = (int)xf;
    int y1 = min(y0 + 1, 63), x1 = min(x0 + 1, 63);
    float wy = ys - (float)y0, wx = xf - (float)x0;
    float w00 = (1.f - wy) * (1.f - wx), w01 = (1.f - wy) * wx;
    float w10 = wy * (1.f - wx), w11 = wy * wx;
    const unsigned short* base = XT + (size_t)b * 4096 * 256 + icg * 32;
    const bf16x8* p00 = (const bf16x8*)(base + (size_t)(y0 * 64 + x0) * 256);
    const bf16x8* p01 = (const bf16x8*)(base + (size_t)(y0 * 64 + x1) * 256);
    const bf16x8* p10 = (const bf16x8*)(base + (size_t)(y1 * 64 + x0) * 256);
    const bf16x8* p11 = (const bf16x8*)(base + (size_t)(y1 * 64 + x1) * 256);
    unsigned short* xo = xds + ((size_t)(b * 256 + j)) * 256 + icg * 32;
#pragma unroll
    for (int q = 0; q < 4; ++q) {
      bf16x8 a00 = p00[q], a01 = p01[q], a10 = p10[q], a11 = p11[q];
      unsigned rp[4];
#pragma unroll
      for (int e2 = 0; e2 < 4; ++e2) {
        float f0 = w00 * bf2f((unsigned short)a00[2*e2])   + w01 * bf2f((unsigned short)a01[2*e2])
                 + w10 * bf2f((unsigned short)a10[2*e2])   + w11 * bf2f((unsigned short)a11[2*e2]);
        float f1 = w00 * bf2f((unsigned short)a00[2*e2+1]) + w01 * bf2f((unsigned short)a01[2*e2+1])
                 + w10 * bf2f((unsigned short)a10[2*e2+1]) + w11 * bf2f((unsigned short)a11[2*e2+1]);
        rp[e2] = (unsigned)f2bf(f0) | ((unsigned)f2bf(f1) << 16);
      }
      uint4 pk = {rp[0], rp[1], rp[2], rp[3]};
      *(uint4*)(xo + q * 8) = pk;
    }
    return;
  }
  int oc0 = blockIdx.y * 128, p0 = blockIdx.x * 128;
  int w = tid >> 6, l = tid & 63;
  int wm = w >> 1, wn = w & 1;
  int lr = l & 15, lg = l >> 4;
  const unsigned short* Wp = W + (size_t)oc0 * 256;
  const unsigned short* Xp = XT + ((size_t)b * 4096 + p0) * 256;
  f32x4 acc[4][4] = {};
  for (int kt = 0; kt < 4; ++kt) {
    int k0 = kt * 64;
#pragma unroll
    for (int j = 0; j < 4; ++j) {
      int chunk = w * 4 + j;            // wave-uniform
      int row = chunk * 8 + (l >> 3);
      int lcu = (l & 7) ^ (row & 7);    // inverse-swizzled source column
      gl_lds16(Wp + (size_t)row * 256 + k0 + lcu * 8, &As[chunk * 512]);
      gl_lds16(Xp + (size_t)row * 256 + k0 + lcu * 8, &Bs[chunk * 512]);
    }
    __syncthreads();
#pragma unroll
    for (int ks = 0; ks < 2; ++ks) {
      bf16x8 af[4], bfr[4];
      int ku = ks * 4 + lg;
#pragma unroll
      for (int mi = 0; mi < 4; ++mi) {
        int row = wm * 64 + mi * 16 + lr;
        af[mi] = *(const bf16x8*)&As[row * 64 + (ku ^ (row & 7)) * 8];
      }
#pragma unroll
      for (int ni = 0; ni < 4; ++ni) {
        int row = wn * 64 + ni * 16 + lr;
        bfr[ni] = *(const bf16x8*)&Bs[row * 64 + (ku ^ (row & 7)) * 8];
      }
#pragma unroll
      for (int mi = 0; mi < 4; ++mi)
#pragma unroll
        for (int ni = 0; ni < 4; ++ni)
          acc[mi][ni] = __builtin_amdgcn_mfma_f32_16x16x32_bf16(
              af[mi], bfr[ni], acc[mi][ni], 0, 0, 0);
    }
    __syncthreads();
  }
  // D: col(l&15) = p-local, row((l>>4)*4+reg) = oc-local
  if constexpr (OUT_BF16) {
    unsigned short (*Cs)[136] = (unsigned short(*)[136])smem;  // union, post-sync
#pragma unroll
    for (int mi = 0; mi < 4; ++mi)
#pragma unroll
      for (int ni = 0; ni < 4; ++ni)
#pragma unroll
        for (int r = 0; r < 4; ++r)
          Cs[wm * 64 + mi * 16 + lg * 4 + r][wn * 64 + ni * 16 + lr] =
              f2bf(acc[mi][ni][r]);
    __syncthreads();
    unsigned short* Yb = (unsigned short*)Yv + (size_t)b * OC * HW_;
    int pc = tid & 15, ocr = tid >> 4;
#pragma unroll
    for (int it = 0; it < 8; ++it) {
      int oc = it * 16 + ocr;
      uint4 pk = *(const uint4*)&Cs[oc][pc * 8];
      *(uint4*)(Yb + (size_t)(oc0 + oc) * HW_ + p0 + pc * 8) = pk;
    }
  } else {
    float* Yb = (float*)Yv + (size_t)b * OC * HW_;
#pragma unroll
    for (int mi = 0; mi < 4; ++mi)
#pragma unroll
      for (int ni = 0; ni < 4; ++ni)
#pragma unroll
        for (int r = 0; r < 4; ++r) {
          int oc = oc0 + wm * 64 + mi * 16 + lg * 4 + r;
          int p  = p0 + wn * 64 + ni * 16 + lr;
          Yb[(size_t)oc * HW_ + p] = acc[mi][ni][r];
        }
  }
}

// ---------- kv GEMM on XDS: 128x128x256 MFMA + LN/vfrag epilogue ----------
__global__ __launch_bounds__(256) void kv_gemm_kernel(
    const unsigned short* __restrict__ XDS, const unsigned short* __restrict__ W,
    const float* __restrict__ gk, const float* __restrict__ bk,
    unsigned short* __restrict__ kln, unsigned short* __restrict__ vfrag) {
  __shared__ unsigned short smem[18432];
  unsigned short* As = smem;
  unsigned short* Bs = smem + 8192;
  int tid = threadIdx.x;
  int b = blockIdx.z, yv = blockIdx.y;
  int oc0 = yv * 128, p0 = blockIdx.x * 128;
  int w = tid >> 6, l = tid & 63;
  int wm = w >> 1, wn = w & 1;
  int lr = l & 15, lg = l >> 4;
  const unsigned short* Wp = W + (size_t)oc0 * 256;
  const unsigned short* Xp = XDS + ((size_t)b * 256 + p0) * 256;
  f32x4 acc[4][4] = {};
  for (int kt = 0; kt < 4; ++kt) {
    int k0 = kt * 64;
#pragma unroll
    for (int j = 0; j < 4; ++j) {
      int chunk = w * 4 + j;
      int row = chunk * 8 + (l >> 3);
      int lcu = (l & 7) ^ (row & 7);
      gl_lds16(Wp + (size_t)row * 256 + k0 + lcu * 8, &As[chunk * 512]);
      gl_lds16(Xp + (size_t)row * 256 + k0 + lcu * 8, &Bs[chunk * 512]);
    }
    __syncthreads();
#pragma unroll
    for (int ks = 0; ks < 2; ++ks) {
      bf16x8 af[4], bfr[4];
      int ku = ks * 4 + lg;
#pragma unroll
      for (int mi = 0; mi < 4; ++mi) {
        int row = wm * 64 + mi * 16 + lr;
        af[mi] = *(const bf16x8*)&As[row * 64 + (ku ^ (row & 7)) * 8];
      }
#pragma unroll
      for (int ni = 0; ni < 4; ++ni) {
        int row = wn * 64 + ni * 16 + lr;
        bfr[ni] = *(const bf16x8*)&Bs[row * 64 + (ku ^ (row & 7)) * 8];
      }
#pragma unroll
      for (int mi = 0; mi < 4; ++mi)
#pragma unroll
        for (int ni = 0; ni < 4; ++ni)
          acc[mi][ni] = __builtin_amdgcn_mfma_f32_16x16x32_bf16(
              af[mi], bfr[ni], acc[mi][ni], 0, 0, 0);
    }
    __syncthreads();
  }
  unsigned short (*Cs)[136] = (unsigned short(*)[136])smem;
#pragma unroll
  for (int mi = 0; mi < 4; ++mi)
#pragma unroll
    for (int ni = 0; ni < 4; ++ni)
#pragma unroll
      for (int r = 0; r < 4; ++r)
        Cs[wm * 64 + mi * 16 + lg * 4 + r][wn * 64 + ni * 16 + lr] =
            f2bf(acc[mi][ni][r]);
  __syncthreads();
  int hl = tid >> 6;          // wave id = h-local
  int jl = tid & 63;
  if (yv < 2) {
    int h = yv * 4 + hl;
    int bh = b * 8 + h;
#pragma unroll
    for (int jj = 0; jj < 2; ++jj) {
      int jc = jl * 2 + jj;
      int j = p0 + jc;
      float v[32];
      float s1 = 0.f, s2 = 0.f;
#pragma unroll
      for (int d = 0; d < 32; ++d) {
        v[d] = bf2f(Cs[hl * 32 + d][jc]);
        s1 += v[d]; s2 += v[d] * v[d];
      }
      float mu = s1 * (1.f / 32.f);
      float var = s2 * (1.f / 32.f) - mu * mu;
      float inv = 1.0f / sqrtf(var + 1e-6f);
      unsigned rp[16];
#pragma unroll
      for (int t = 0; t < 16; ++t) {
        float y0f = (v[2*t]   - mu) * inv * gk[h*32 + 2*t]   + bk[h*32 + 2*t];
        float y1f = (v[2*t+1] - mu) * inv * gk[h*32 + 2*t+1] + bk[h*32 + 2*t+1];
        rp[t] = (unsigned)f2bf(y0f) | ((unsigned)f2bf(y1f) << 16);
      }
      uint4* ko = (uint4*)(kln + ((size_t)bh * 256 + j) * 32);
#pragma unroll
      for (int t4 = 0; t4 < 4; ++t4) {
        uint4 pk = {rp[t4*4], rp[t4*4+1], rp[t4*4+2], rp[t4*4+3]};
        ko[t4] = pk;
      }
    }
  } else {
    int h = (yv - 2) * 4 + hl;
    int bh = b * 8 + h;
#pragma unroll
    for (int jj = 0; jj < 2; ++jj) {
      int jc = jl * 2 + jj;
      int j = p0 + jc;
      int c = j >> 4, gq2 = (j >> 2) & 3, ii = j & 3;
      unsigned short* vo = vfrag + (size_t)bh * 8192;
#pragma unroll
      for (int d = 0; d < 32; ++d) {
        int dt = d >> 4, dr = d & 15;
        vo[(c * 2 + dt) * 256 + (gq2 * 16 + dr) * 4 + ii] = Cs[hl * 32 + d][jc];
      }
    }
  }
}

// ---------------- MFMA attention: LDS-staged q tile + fused q-LayerNorm ----------
__global__ __launch_bounds__(256) void attn_mfma_kernel(
    const unsigned short* __restrict__ qb, const float* __restrict__ gq,
    const float* __restrict__ bq, const unsigned short* __restrict__ kln,
    const unsigned short* __restrict__ vfrag, const float* __restrict__ bias_pre,
    float* __restrict__ attn_out, unsigned short* __restrict__ out_nchw) {
  __shared__ unsigned short qs[32][66];   // q tile: row d, col q-local (padded)
  __shared__ unsigned short sT[32][72];   // out stage (16B-aligned rows)
  int tile = blockIdx.x, h = blockIdx.y, b = blockIdx.z;
  int bh = b * 8 + h;
  int tid = threadIdx.x;
  int w = tid >> 6, l = tid & 63;
  int lr = l & 15, lg = l >> 4;
  int qbase = tile * 64 + w * 16;
  int q = qbase + lr;
  int iy = q >> 6, ix = q & 63;
  int g = (iy >> 2) * 16 + (ix >> 2);

  // cooperative q tile load: 32 rows (d) x 64 q-pixels, each row 128 B contiguous
  {
    const unsigned short* qrow = qb + (size_t)b * 256 * HW_ + tile * 64;
#pragma unroll
    for (int it = 0; it < 4; ++it) {
      int flat = tid + it * 256;        // 0..1023
      int d = flat >> 5;                // 0..31
      int cp = flat & 31;               // col pair (2 ushorts)
      *(unsigned*)&qs[d][cp * 2] =
          *(const unsigned*)(qrow + (size_t)(d * 8 + h) * HW_ + cp * 2);
    }
  }
  __syncthreads();

  // fused q LayerNorm from LDS
  float qv[8];
  float sum = 0.f, sum2 = 0.f;
#pragma unroll
  for (int e = 0; e < 8; ++e) {
    qv[e] = bf2f(qs[lg * 8 + e][w * 16 + lr]);
    sum += qv[e]; sum2 += qv[e] * qv[e];
  }
  sum  += __shfl_xor(sum, 16, 64);  sum  += __shfl_xor(sum, 32, 64);
  sum2 += __shfl_xor(sum2, 16, 64); sum2 += __shfl_xor(sum2, 32, 64);
  float mu = sum * (1.f / 32.f);
  float var = sum2 * (1.f / 32.f) - mu * mu;
  float inv = 1.0f / sqrtf(var + 1e-6f);
  bf16x8 qf;
#pragma unroll
  for (int e = 0; e < 8; ++e) {
    int d = lg * 8 + e;
    float y = (qv[e] - mu) * inv * gq[h * 32 + d] + bq[h * 32 + d];
    qf[e] = (short)f2bf(y);
  }

  const unsigned short* kbase = kln + (size_t)bh * 256 * 32 + lr * 32 + lg * 8;
  const unsigned short* vbase = vfrag + (size_t)bh * 32 * 256 + l * 4;
  const float* bbase = bias_pre + ((size_t)h * 256 + g) * 256 + lg * 4;
  float* abase = attn_out + ((size_t)bh * 4096 + q) * 256 + lg * 4;

  f32x4 z = {0.f, 0.f, 0.f, 0.f};
  f32x4 oacc0 = z, oacc1 = z;
#pragma unroll
  for (int c = 0; c < 16; ++c) {
    bf16x8 kf = *(const bf16x8*)(kbase + c * 16 * 32);
    f32x4 s = __builtin_amdgcn_mfma_f32_16x16x32_bf16(kf, qf, z, 0, 0, 0);
    f32x4 bias = *(const f32x4*)(bbase + c * 16);
    f32x4 t = s * 0.03125f + bias;
    __builtin_nontemporal_store(t, (f32x4*)(abase + c * 16));
    bf16x4 pb;
    pb[0] = (short)f2bf(t.x);
    pb[1] = (short)f2bf(t.y);
    pb[2] = (short)f2bf(t.z);
    pb[3] = (short)f2bf(t.w);
    bf16x4 va0 = *(const bf16x4*)(vbase + (c * 2 + 0) * 256);
    bf16x4 va1 = *(const bf16x4*)(vbase + (c * 2 + 1) * 256);
    oacc0 = __builtin_amdgcn_mfma_f32_16x16x16bf16_1k(va0, pb, oacc0, 0, 0, 0);
    oacc1 = __builtin_amdgcn_mfma_f32_16x16x16bf16_1k(va1, pb, oacc1, 0, 0, 0);
  }
  // stage out tile [32 d][64 q] in LDS, then 128-B coalesced stores
  float ov[8] = {oacc0.x, oacc0.y, oacc0.z, oacc0.w,
                 oacc1.x, oacc1.y, oacc1.z, oacc1.w};
#pragma unroll
  for (int dt = 0; dt < 2; ++dt)
#pragma unroll
    for (int r = 0; r < 4; ++r)
      sT[dt * 16 + lg * 4 + r][w * 16 + lr] = f2bf(ov[dt * 4 + r]);
  __syncthreads();
  {
    int row = tid >> 3, seg = tid & 7;       // 32 d-rows x 8 segs x 16 B
    uint4 pk = *(const uint4*)&sT[row][seg * 8];
    int cc = row * 8 + h;
    *(uint4*)(out_nchw + ((size_t)b * 256 + cc) * HW_ + tile * 64 + seg * 8) = pk;
  }
}

extern "C" void kernel_launch(void* const* d_in, const int* in_sizes, int n_in,
                              void* d_out, int out_size, void* d_ws, size_t ws_size,
                              hipStream_t stream) {
  const float* x      = (const float*)d_in[0];
  const float* qkv_dw = (const float*)d_in[1];
  const float* qkv_pw = (const float*)d_in[2];
  const float* out_dw = (const float*)d_in[3];
  const float* out_pw = (const float*)d_in[4];
  const float* gq     = (const float*)d_in[5];
  const float* bq     = (const float*)d_in[6];
  const float* gk     = (const float*)d_in[7];
  const float* bk     = (const float*)d_in[8];
  const float* btab   = (const float*)d_in[9];
  const int*   relidx = (const int*)d_in[10];

  float* out  = (float*)d_out;            // 8,388,608 floats
  float* attn = out + 8388608;            // 67,108,864 floats (268 MB)

  unsigned short* us = (unsigned short*)d_ws;
  unsigned short* xT1    = us;                    // 16.8 MB
  unsigned short* xT2    = us + 8388608;          // 16.8 MB
  unsigned short* onchwb = us + 16777216;         // 16.8 MB
  unsigned short* kln    = us + 25165824;         // 1 MB
  unsigned short* vfrag  = us + 25690112;         // 1 MB
  unsigned short* wbuf   = us + 26214400;         // 0.5 MB
  float* bias_pre = (float*)(us + 26476544);      // 2 MB
  unsigned short* qb     = us + 27525120;         // 16.8 MB (q only)
  unsigned short* xds    = us + 35913728;         // 1 MB

  dwconv_t_kernel<float, 1><<<dim3(64, 4, 9), 256, 0, stream>>>(
      x, qkv_dw, xT1, qkv_pw, out_pw, wbuf, btab, relidx, bias_pre);
  pwconv_mfma_kernel<1, 1><<<dim3(32, 3, 8), 256, 0, stream>>>(
      xT1, wbuf, qb, 256, xds);
  kv_gemm_kernel<<<dim3(2, 4, 8), 256, 0, stream>>>(
      xds, wbuf + 65536, gk, bk, kln, vfrag);
  attn_mfma_kernel<<<dim3(64, 8, 8), 256, 0, stream>>>(qb, gq, bq, kln, vfrag,
                                                       bias_pre, attn, onchwb);
  dwconv_t_kernel<unsigned short, 0><<<dim3(64, 4, 8), 256, 0, stream>>>(
      onchwb, out_dw, xT2, nullptr, nullptr, nullptr, nullptr, nullptr, nullptr);
  pwconv_mfma_kernel<0, 0><<<dim3(32, 2, 8), 256, 0, stream>>>(
      xT2, wbuf + 196608, out, 256, nullptr);
}